// Round 1
// baseline (1061.123 us; speedup 1.0000x reference)
//
#include <hip/hip_runtime.h>
#include <math.h>

#define B_ 4
#define P_ 64
#define D_ 768
#define N_ 2048
#define R_ 12
#define K_ 16
#define Q_ 256  // B_*P_

// ---------------- K1: normalize key rows (N rows of D) ----------------
__global__ __launch_bounds__(256) void k_norm(const float* __restrict__ kp,
                                              float* __restrict__ keys) {
    int row = blockIdx.x;
    int tid = threadIdx.x;
    const float* src = kp + (size_t)row * D_;
    float x0 = src[tid], x1 = src[tid + 256], x2 = src[tid + 512];
    float ss = x0 * x0 + x1 * x1 + x2 * x2;
    #pragma unroll
    for (int off = 32; off > 0; off >>= 1) ss += __shfl_down(ss, off, 64);
    __shared__ float sm[4];
    if ((tid & 63) == 0) sm[tid >> 6] = ss;
    __syncthreads();
    float tot = sm[0] + sm[1] + sm[2] + sm[3];
    float inv = 1.0f / sqrtf(tot + 1e-12f);
    float* dst = keys + (size_t)row * D_;
    dst[tid] = x0 * inv;
    dst[tid + 256] = x1 * inv;
    dst[tid + 512] = x2 * inv;
}

// ---------------- K2: scores = positions (256xD) @ keys^T (NxD) --------
// f32 (top-k selection is precision-critical). Tile 32q x 64n, BK=64.
__global__ __launch_bounds__(256) void k_scores(const float* __restrict__ pos,
                                                const float* __restrict__ keys,
                                                float* __restrict__ scores) {
    __shared__ float As[32][65];
    __shared__ float Bs[64][65];
    int tid = threadIdx.x;
    int q0 = blockIdx.y * 32;
    int n0 = blockIdx.x * 64;
    int tr = tid >> 4, tc = tid & 15;
    float acc[2][4] = {};
    for (int kb = 0; kb < D_; kb += 64) {
        #pragma unroll
        for (int e = tid; e < 512; e += 256) {
            int row = e >> 4, c4 = e & 15;
            const float4 v = *(const float4*)(pos + (size_t)(q0 + row) * D_ + kb + c4 * 4);
            float* d = &As[row][c4 * 4];
            d[0] = v.x; d[1] = v.y; d[2] = v.z; d[3] = v.w;
        }
        #pragma unroll
        for (int e = tid; e < 1024; e += 256) {
            int row = e >> 4, c4 = e & 15;
            const float4 v = *(const float4*)(keys + (size_t)(n0 + row) * D_ + kb + c4 * 4);
            float* d = &Bs[row][c4 * 4];
            d[0] = v.x; d[1] = v.y; d[2] = v.z; d[3] = v.w;
        }
        __syncthreads();
        for (int kk = 0; kk < 64; kk++) {
            float a0 = As[2 * tr][kk], a1 = As[2 * tr + 1][kk];
            #pragma unroll
            for (int c = 0; c < 4; c++) {
                float b = Bs[tc * 4 + c][kk];
                acc[0][c] += a0 * b;
                acc[1][c] += a1 * b;
            }
        }
        __syncthreads();
    }
    #pragma unroll
    for (int i = 0; i < 2; i++)
        #pragma unroll
        for (int c = 0; c < 4; c++)
            scores[(size_t)(q0 + 2 * tr + i) * N_ + n0 + tc * 4 + c] = acc[i][c];
}

// ---------------- K3: top-16 + softmax per query ----------------
__global__ __launch_bounds__(256) void k_topk(const float* __restrict__ scores,
                                              float* __restrict__ wout,
                                              int* __restrict__ iout) {
    int q = blockIdx.x, tid = threadIdx.x;
    __shared__ float s[N_];
    __shared__ float rv[4];
    __shared__ int ri[4];
    __shared__ float lv[K_];
    __shared__ int li[K_];
    #pragma unroll
    for (int i = 0; i < 8; i++) s[tid + i * 256] = scores[(size_t)q * N_ + tid + i * 256];
    __syncthreads();
    for (int r = 0; r < K_; r++) {
        float bv = -3.0e38f;
        int bi = 0;
        #pragma unroll
        for (int i = 0; i < 8; i++) {
            int j = tid + i * 256;
            float v = s[j];
            if (v > bv) { bv = v; bi = j; }
        }
        #pragma unroll
        for (int off = 32; off > 0; off >>= 1) {
            float ov = __shfl_down(bv, off, 64);
            int oi = __shfl_down(bi, off, 64);
            if (ov > bv || (ov == bv && oi < bi)) { bv = ov; bi = oi; }
        }
        if ((tid & 63) == 0) { rv[tid >> 6] = bv; ri[tid >> 6] = bi; }
        __syncthreads();
        if (tid == 0) {
            float mv = rv[0];
            int mi = ri[0];
            for (int w2 = 1; w2 < 4; w2++)
                if (rv[w2] > mv || (rv[w2] == mv && ri[w2] < mi)) { mv = rv[w2]; mi = ri[w2]; }
            lv[r] = mv; li[r] = mi;
            s[mi] = -3.0e38f;
        }
        __syncthreads();
    }
    if (tid == 0) {
        float m = lv[0];
        float e[K_];
        float sum = 0.f;
        for (int i = 0; i < K_; i++) { e[i] = expf(lv[i] - m); sum += e[i]; }
        float isum = 1.0f / sum;
        for (int i = 0; i < K_; i++) {
            wout[q * K_ + i] = e[i] * isum;
            iout[q * K_ + i] = li[i];
        }
    }
}

// ---------------- K4: A_sum[n,m] = sum_r adjacency[r,n,m] --------------
__global__ __launch_bounds__(256) void k_asum(const float* __restrict__ adj,
                                              float* __restrict__ asum) {
    size_t i = (size_t)blockIdx.x * 256 + threadIdx.x;  // float4 index, total N*N/4
    const float4* a4 = (const float4*)adj;
    const size_t plane = (size_t)N_ * N_ / 4;
    float4 acc = {0.f, 0.f, 0.f, 0.f};
    #pragma unroll
    for (int r = 0; r < R_; r++) {
        float4 v = a4[(size_t)r * plane + i];
        acc.x += v.x; acc.y += v.y; acc.z += v.z; acc.w += v.w;
    }
    ((float4*)asum)[i] = acc;
}

// ---------------- K5: nei[q,:] = sum_k w_k * A_sum[idx_k,:] ------------
__global__ __launch_bounds__(256) void k_nei(const float* __restrict__ asum,
                                             const float* __restrict__ wv,
                                             const int* __restrict__ iv,
                                             float* __restrict__ nei) {
    int q = blockIdx.x, tid = threadIdx.x;
    __shared__ float wi[K_];
    __shared__ int ii[K_];
    if (tid < K_) { wi[tid] = wv[q * K_ + tid]; ii[tid] = iv[q * K_ + tid]; }
    __syncthreads();
    float4 acc0 = {0.f, 0.f, 0.f, 0.f};
    float4 acc1 = {0.f, 0.f, 0.f, 0.f};
    #pragma unroll
    for (int k = 0; k < K_; k++) {
        const float4* row = (const float4*)(asum + (size_t)ii[k] * N_);
        float wk = wi[k];
        float4 v0 = row[tid], v1 = row[tid + 256];
        acc0.x += wk * v0.x; acc0.y += wk * v0.y; acc0.z += wk * v0.z; acc0.w += wk * v0.w;
        acc1.x += wk * v1.x; acc1.y += wk * v1.y; acc1.z += wk * v1.z; acc1.w += wk * v1.w;
    }
    float4* dst = (float4*)(nei + (size_t)q * N_);
    dst[tid] = acc0;
    dst[tid + 256] = acc1;
}

// ---------------- K6: out = nei (256xN) @ keys (NxD), split-K=8 --------
__global__ __launch_bounds__(256) void k_out(const float* __restrict__ nei,
                                             const float* __restrict__ keys,
                                             float* __restrict__ out) {
    __shared__ float As[32][65];
    __shared__ float Bs[64][64];
    int tid = threadIdx.x;
    int d0 = blockIdx.x * 64;
    int q0 = blockIdx.y * 32;
    int kb0 = blockIdx.z * 256;
    int tr = tid >> 4, tc = tid & 15;
    float acc[2][4] = {};
    for (int kb = kb0; kb < kb0 + 256; kb += 64) {
        #pragma unroll
        for (int e = tid; e < 512; e += 256) {
            int row = e >> 4, c4 = e & 15;
            const float4 v = *(const float4*)(nei + (size_t)(q0 + row) * N_ + kb + c4 * 4);
            float* d = &As[row][c4 * 4];
            d[0] = v.x; d[1] = v.y; d[2] = v.z; d[3] = v.w;
        }
        #pragma unroll
        for (int e = tid; e < 1024; e += 256) {
            int row = e >> 4, c4 = e & 15;  // row indexes kk
            const float4 v = *(const float4*)(keys + (size_t)(kb + row) * D_ + d0 + c4 * 4);
            float* d = &Bs[row][c4 * 4];
            d[0] = v.x; d[1] = v.y; d[2] = v.z; d[3] = v.w;
        }
        __syncthreads();
        for (int kk = 0; kk < 64; kk++) {
            float a0 = As[2 * tr][kk], a1 = As[2 * tr + 1][kk];
            #pragma unroll
            for (int c = 0; c < 4; c++) {
                float b = Bs[kk][tc * 4 + c];
                acc[0][c] += a0 * b;
                acc[1][c] += a1 * b;
            }
        }
        __syncthreads();
    }
    #pragma unroll
    for (int i = 0; i < 2; i++)
        #pragma unroll
        for (int c = 0; c < 4; c++)
            atomicAdd(&out[(size_t)(q0 + 2 * tr + i) * D_ + d0 + tc * 4 + c], acc[i][c]);
}

extern "C" void kernel_launch(void* const* d_in, const int* in_sizes, int n_in,
                              void* d_out, int out_size, void* d_ws, size_t ws_size,
                              hipStream_t stream) {
    const float* pos = (const float*)d_in[0];   // (4,64,768)
    const float* kp  = (const float*)d_in[1];   // (2048,768)
    const float* adj = (const float*)d_in[2];   // (12,2048,2048)
    // d_in[3] is k==16, hard-coded.
    float* out = (float*)d_out;

    float* ws     = (float*)d_ws;
    float* keys   = ws;                              // 1,572,864 f
    float* asum   = keys + (size_t)N_ * D_;          // 4,194,304 f
    float* scores = asum + (size_t)N_ * N_;          //   524,288 f
    float* nei    = scores + (size_t)Q_ * N_;        //   524,288 f
    float* wbuf   = nei + (size_t)Q_ * N_;           //     4,096 f
    int*   ibuf   = (int*)(wbuf + Q_ * K_);          //     4,096 i
    // total ~27.3 MB of workspace

    hipMemsetAsync(d_out, 0, (size_t)out_size * sizeof(float), stream);
    k_norm<<<N_, 256, 0, stream>>>(kp, keys);
    k_scores<<<dim3(32, 8), 256, 0, stream>>>(pos, keys, scores);
    k_topk<<<Q_, 256, 0, stream>>>(scores, wbuf, ibuf);
    k_asum<<<4096, 256, 0, stream>>>(adj, asum);
    k_nei<<<Q_, 256, 0, stream>>>(asum, wbuf, ibuf, nei);
    k_out<<<dim3(12, 8, 8), 256, 0, stream>>>(nei, keys, out);
}

// Round 2
// 631.891 us; speedup vs baseline: 1.6793x; 1.6793x over previous
//
#include <hip/hip_runtime.h>
#include <math.h>

#define B_ 4
#define P_ 64
#define D_ 768
#define N_ 2048
#define R_ 12
#define K_ 16
#define Q_ 256  // B_*P_
#define SPLITS_ 8

// ---------------- K1: normalize key rows (N rows of D) ----------------
__global__ __launch_bounds__(256) void k_norm(const float* __restrict__ kp,
                                              float* __restrict__ keys) {
    int row = blockIdx.x;
    int tid = threadIdx.x;
    const float* src = kp + (size_t)row * D_;
    float x0 = src[tid], x1 = src[tid + 256], x2 = src[tid + 512];
    float ss = x0 * x0 + x1 * x1 + x2 * x2;
    #pragma unroll
    for (int off = 32; off > 0; off >>= 1) ss += __shfl_down(ss, off, 64);
    __shared__ float sm[4];
    if ((tid & 63) == 0) sm[tid >> 6] = ss;
    __syncthreads();
    float tot = sm[0] + sm[1] + sm[2] + sm[3];
    float inv = 1.0f / sqrtf(tot + 1e-12f);
    float* dst = keys + (size_t)row * D_;
    dst[tid] = x0 * inv;
    dst[tid + 256] = x1 * inv;
    dst[tid + 512] = x2 * inv;
}

// ---------------- K2: scores = positions (256xD) @ keys^T (NxD) --------
// f32 (top-k selection is precision-critical). Tile 32q x 64n, BK=64.
__global__ __launch_bounds__(256) void k_scores(const float* __restrict__ pos,
                                                const float* __restrict__ keys,
                                                float* __restrict__ scores) {
    __shared__ float As[32][65];
    __shared__ float Bs[64][65];
    int tid = threadIdx.x;
    int q0 = blockIdx.y * 32;
    int n0 = blockIdx.x * 64;
    int tr = tid >> 4, tc = tid & 15;
    float acc[2][4] = {};
    for (int kb = 0; kb < D_; kb += 64) {
        #pragma unroll
        for (int e = tid; e < 512; e += 256) {
            int row = e >> 4, c4 = e & 15;
            const float4 v = *(const float4*)(pos + (size_t)(q0 + row) * D_ + kb + c4 * 4);
            float* d = &As[row][c4 * 4];
            d[0] = v.x; d[1] = v.y; d[2] = v.z; d[3] = v.w;
        }
        #pragma unroll
        for (int e = tid; e < 1024; e += 256) {
            int row = e >> 4, c4 = e & 15;
            const float4 v = *(const float4*)(keys + (size_t)(n0 + row) * D_ + kb + c4 * 4);
            float* d = &Bs[row][c4 * 4];
            d[0] = v.x; d[1] = v.y; d[2] = v.z; d[3] = v.w;
        }
        __syncthreads();
        for (int kk = 0; kk < 64; kk++) {
            float a0 = As[2 * tr][kk], a1 = As[2 * tr + 1][kk];
            #pragma unroll
            for (int c = 0; c < 4; c++) {
                float b = Bs[tc * 4 + c][kk];
                acc[0][c] += a0 * b;
                acc[1][c] += a1 * b;
            }
        }
        __syncthreads();
    }
    #pragma unroll
    for (int i = 0; i < 2; i++)
        #pragma unroll
        for (int c = 0; c < 4; c++)
            scores[(size_t)(q0 + 2 * tr + i) * N_ + n0 + tc * 4 + c] = acc[i][c];
}

// ---------------- K3: top-16 + softmax per query ----------------
__global__ __launch_bounds__(256) void k_topk(const float* __restrict__ scores,
                                              float* __restrict__ wout,
                                              int* __restrict__ iout) {
    int q = blockIdx.x, tid = threadIdx.x;
    __shared__ float s[N_];
    __shared__ float rv[4];
    __shared__ int ri[4];
    __shared__ float lv[K_];
    __shared__ int li[K_];
    #pragma unroll
    for (int i = 0; i < 8; i++) s[tid + i * 256] = scores[(size_t)q * N_ + tid + i * 256];
    __syncthreads();
    for (int r = 0; r < K_; r++) {
        float bv = -3.0e38f;
        int bi = 0;
        #pragma unroll
        for (int i = 0; i < 8; i++) {
            int j = tid + i * 256;
            float v = s[j];
            if (v > bv) { bv = v; bi = j; }
        }
        #pragma unroll
        for (int off = 32; off > 0; off >>= 1) {
            float ov = __shfl_down(bv, off, 64);
            int oi = __shfl_down(bi, off, 64);
            if (ov > bv || (ov == bv && oi < bi)) { bv = ov; bi = oi; }
        }
        if ((tid & 63) == 0) { rv[tid >> 6] = bv; ri[tid >> 6] = bi; }
        __syncthreads();
        if (tid == 0) {
            float mv = rv[0];
            int mi = ri[0];
            for (int w2 = 1; w2 < 4; w2++)
                if (rv[w2] > mv || (rv[w2] == mv && ri[w2] < mi)) { mv = rv[w2]; mi = ri[w2]; }
            lv[r] = mv; li[r] = mi;
            s[mi] = -3.0e38f;
        }
        __syncthreads();
    }
    if (tid == 0) {
        float m = lv[0];
        float e[K_];
        float sum = 0.f;
        for (int i = 0; i < K_; i++) { e[i] = expf(lv[i] - m); sum += e[i]; }
        float isum = 1.0f / sum;
        for (int i = 0; i < K_; i++) {
            wout[q * K_ + i] = e[i] * isum;
            iout[q * K_ + i] = li[i];
        }
    }
}

// ---------------- K4: A_sum[n,m] = sum_r adjacency[r,n,m] --------------
__global__ __launch_bounds__(256) void k_asum(const float* __restrict__ adj,
                                              float* __restrict__ asum) {
    size_t i = (size_t)blockIdx.x * 256 + threadIdx.x;  // float4 index, total N*N/4
    const float4* a4 = (const float4*)adj;
    const size_t plane = (size_t)N_ * N_ / 4;
    float4 acc = {0.f, 0.f, 0.f, 0.f};
    #pragma unroll
    for (int r = 0; r < R_; r++) {
        float4 v = a4[(size_t)r * plane + i];
        acc.x += v.x; acc.y += v.y; acc.z += v.z; acc.w += v.w;
    }
    ((float4*)asum)[i] = acc;
}

// ---------------- K5: nei[q,:] = sum_k w_k * A_sum[idx_k,:] ------------
__global__ __launch_bounds__(256) void k_nei(const float* __restrict__ asum,
                                             const float* __restrict__ wv,
                                             const int* __restrict__ iv,
                                             float* __restrict__ nei) {
    int q = blockIdx.x, tid = threadIdx.x;
    __shared__ float wi[K_];
    __shared__ int ii[K_];
    if (tid < K_) { wi[tid] = wv[q * K_ + tid]; ii[tid] = iv[q * K_ + tid]; }
    __syncthreads();
    float4 acc0 = {0.f, 0.f, 0.f, 0.f};
    float4 acc1 = {0.f, 0.f, 0.f, 0.f};
    #pragma unroll
    for (int k = 0; k < K_; k++) {
        const float4* row = (const float4*)(asum + (size_t)ii[k] * N_);
        float wk = wi[k];
        float4 v0 = row[tid], v1 = row[tid + 256];
        acc0.x += wk * v0.x; acc0.y += wk * v0.y; acc0.z += wk * v0.z; acc0.w += wk * v0.w;
        acc1.x += wk * v1.x; acc1.y += wk * v1.y; acc1.z += wk * v1.z; acc1.w += wk * v1.w;
    }
    float4* dst = (float4*)(nei + (size_t)q * N_);
    dst[tid] = acc0;
    dst[tid + 256] = acc1;
}

// ---------------- K6: out_part[z] = nei (256x256-slice) @ keys ---------
// Split-K=8 into PRIVATE partial buffers (plain stores, NO atomics: device
// atomics ping-pong lines across non-coherent XCD L2s -> 1.5 GB HBM traffic).
__global__ __launch_bounds__(256) void k_out_part(const float* __restrict__ nei,
                                                  const float* __restrict__ keys,
                                                  float* __restrict__ part) {
    __shared__ float As[32][65];
    __shared__ float Bs[64][64];
    int tid = threadIdx.x;
    int d0 = blockIdx.x * 64;
    int q0 = blockIdx.y * 32;
    int z  = blockIdx.z;
    int kb0 = z * (N_ / SPLITS_);
    int tr = tid >> 4, tc = tid & 15;
    float acc[2][4] = {};
    for (int kb = kb0; kb < kb0 + N_ / SPLITS_; kb += 64) {
        #pragma unroll
        for (int e = tid; e < 512; e += 256) {
            int row = e >> 4, c4 = e & 15;
            const float4 v = *(const float4*)(nei + (size_t)(q0 + row) * N_ + kb + c4 * 4);
            float* d = &As[row][c4 * 4];
            d[0] = v.x; d[1] = v.y; d[2] = v.z; d[3] = v.w;
        }
        #pragma unroll
        for (int e = tid; e < 1024; e += 256) {
            int row = e >> 4, c4 = e & 15;  // row indexes kk
            const float4 v = *(const float4*)(keys + (size_t)(kb + row) * D_ + d0 + c4 * 4);
            float* d = &Bs[row][c4 * 4];
            d[0] = v.x; d[1] = v.y; d[2] = v.z; d[3] = v.w;
        }
        __syncthreads();
        for (int kk = 0; kk < 64; kk++) {
            float a0 = As[2 * tr][kk], a1 = As[2 * tr + 1][kk];
            #pragma unroll
            for (int c = 0; c < 4; c++) {
                float b = Bs[kk][tc * 4 + c];
                acc[0][c] += a0 * b;
                acc[1][c] += a1 * b;
            }
        }
        __syncthreads();
    }
    float* base = part + (size_t)z * Q_ * D_;
    #pragma unroll
    for (int i = 0; i < 2; i++) {
        float4 v = {acc[i][0], acc[i][1], acc[i][2], acc[i][3]};
        *(float4*)(base + (size_t)(q0 + 2 * tr + i) * D_ + d0 + tc * 4) = v;
    }
}

// ---------------- K7: out = sum_z part[z] ------------------------------
__global__ __launch_bounds__(256) void k_reduce(const float* __restrict__ part,
                                                float* __restrict__ out) {
    int i = blockIdx.x * 256 + threadIdx.x;  // float4 index over Q_*D_/4 = 49152
    const float4* p4 = (const float4*)part;
    const int plane = Q_ * D_ / 4;
    float4 acc = {0.f, 0.f, 0.f, 0.f};
    #pragma unroll
    for (int z = 0; z < SPLITS_; z++) {
        float4 v = p4[(size_t)z * plane + i];
        acc.x += v.x; acc.y += v.y; acc.z += v.z; acc.w += v.w;
    }
    ((float4*)out)[i] = acc;
}

extern "C" void kernel_launch(void* const* d_in, const int* in_sizes, int n_in,
                              void* d_out, int out_size, void* d_ws, size_t ws_size,
                              hipStream_t stream) {
    const float* pos = (const float*)d_in[0];   // (4,64,768)
    const float* kp  = (const float*)d_in[1];   // (2048,768)
    const float* adj = (const float*)d_in[2];   // (12,2048,2048)
    // d_in[3] is k==16, hard-coded.
    float* out = (float*)d_out;

    float* ws     = (float*)d_ws;
    float* keys   = ws;                              // 1,572,864 f
    float* asum   = keys + (size_t)N_ * D_;          // 4,194,304 f (16 MB)
    float* scores = asum + (size_t)N_ * N_;          //   524,288 f
    float* nei    = scores + (size_t)Q_ * N_;        //   524,288 f
    float* wbuf   = nei + (size_t)Q_ * N_;           //     4,096 f
    int*   ibuf   = (int*)(wbuf + Q_ * K_);          //     4,096 i
    // Partial buffers for split-K output GEMM: 8 * 256*768 f = 6 MB.
    // Aliased onto asum (dead after k_nei; same-stream ordering makes it safe).
    float* part   = asum;

    k_norm<<<N_, 256, 0, stream>>>(kp, keys);
    k_scores<<<dim3(32, 8), 256, 0, stream>>>(pos, keys, scores);
    k_topk<<<Q_, 256, 0, stream>>>(scores, wbuf, ibuf);
    k_asum<<<4096, 256, 0, stream>>>(adj, asum);
    k_nei<<<Q_, 256, 0, stream>>>(asum, wbuf, ibuf, nei);
    k_out_part<<<dim3(12, 8, SPLITS_), 256, 0, stream>>>(nei, keys, part);
    k_reduce<<<192, 256, 0, stream>>>(part, out);
}

// Round 3
// 409.548 us; speedup vs baseline: 2.5910x; 1.5429x over previous
//
#include <hip/hip_runtime.h>
#include <math.h>

#define B_ 4
#define P_ 64
#define D_ 768
#define N_ 2048
#define R_ 12
#define K_ 16
#define Q_ 256  // B_*P_
#define SPLITS_ 8
#define BK_ 32

// ---------------- K1: normalize key rows (N rows of D) ----------------
__global__ __launch_bounds__(256) void k_norm(const float* __restrict__ kp,
                                              float* __restrict__ keys) {
    int row = blockIdx.x;
    int tid = threadIdx.x;
    const float* src = kp + (size_t)row * D_;
    float x0 = src[tid], x1 = src[tid + 256], x2 = src[tid + 512];
    float ss = x0 * x0 + x1 * x1 + x2 * x2;
    #pragma unroll
    for (int off = 32; off > 0; off >>= 1) ss += __shfl_down(ss, off, 64);
    __shared__ float sm[4];
    if ((tid & 63) == 0) sm[tid >> 6] = ss;
    __syncthreads();
    float tot = sm[0] + sm[1] + sm[2] + sm[3];
    float inv = 1.0f / sqrtf(tot + 1e-12f);
    float* dst = keys + (size_t)row * D_;
    dst[tid] = x0 * inv;
    dst[tid + 256] = x1 * inv;
    dst[tid + 512] = x2 * inv;
}

// ---------------- K2: scores = positions (256xD) @ keys^T (NxD) --------
// f32 (top-k selection is precision-critical). 64x64 tile, BK=32, 4x4/thread.
// Both operands staged TRANSPOSED (Xst[kk][row]) so the inner loop is two
// ds_read_b128 + 16 v_fma_f32. unroll capped: the old full-unroll version
// hoisted ds_reads until VGPR=256 + scratch spill (512 MB of HBM writes!).
__global__ __launch_bounds__(256) void k_scores(const float* __restrict__ pos,
                                                const float* __restrict__ keys,
                                                float* __restrict__ scores) {
    __shared__ float Ast[BK_][68];  // 68: +4 pad keeps 16B align, shifts banks
    __shared__ float Bst[BK_][68];
    int tid = threadIdx.x;
    int tx = tid & 15, ty = tid >> 4;
    int n0 = blockIdx.x * 64, q0 = blockIdx.y * 64;
    float acc[4][4] = {};
    for (int kb = 0; kb < D_; kb += BK_) {
        #pragma unroll
        for (int e = 0; e < 2; e++) {
            int elem = tid + e * 256;
            int row = elem >> 3, c4 = elem & 7;
            float4 v = *(const float4*)(pos + (size_t)(q0 + row) * D_ + kb + c4 * 4);
            Ast[c4 * 4 + 0][row] = v.x; Ast[c4 * 4 + 1][row] = v.y;
            Ast[c4 * 4 + 2][row] = v.z; Ast[c4 * 4 + 3][row] = v.w;
        }
        #pragma unroll
        for (int e = 0; e < 2; e++) {
            int elem = tid + e * 256;
            int row = elem >> 3, c4 = elem & 7;
            float4 v = *(const float4*)(keys + (size_t)(n0 + row) * D_ + kb + c4 * 4);
            Bst[c4 * 4 + 0][row] = v.x; Bst[c4 * 4 + 1][row] = v.y;
            Bst[c4 * 4 + 2][row] = v.z; Bst[c4 * 4 + 3][row] = v.w;
        }
        __syncthreads();
        #pragma unroll 4
        for (int kk = 0; kk < BK_; kk++) {
            float4 a = *(const float4*)&Ast[kk][ty * 4];
            float4 b = *(const float4*)&Bst[kk][tx * 4];
            float av[4] = {a.x, a.y, a.z, a.w};
            float bv[4] = {b.x, b.y, b.z, b.w};
            #pragma unroll
            for (int i = 0; i < 4; i++)
                #pragma unroll
                for (int j = 0; j < 4; j++)
                    acc[i][j] += av[i] * bv[j];
        }
        __syncthreads();
    }
    #pragma unroll
    for (int i = 0; i < 4; i++) {
        float4 v = {acc[i][0], acc[i][1], acc[i][2], acc[i][3]};
        *(float4*)(scores + (size_t)(q0 + ty * 4 + i) * N_ + n0 + tx * 4) = v;
    }
}

// ---------------- K3: top-16 + softmax per query ----------------
__global__ __launch_bounds__(256) void k_topk(const float* __restrict__ scores,
                                              float* __restrict__ wout,
                                              int* __restrict__ iout) {
    int q = blockIdx.x, tid = threadIdx.x;
    __shared__ float s[N_];
    __shared__ float rv[4];
    __shared__ int ri[4];
    __shared__ float lv[K_];
    __shared__ int li[K_];
    #pragma unroll
    for (int i = 0; i < 8; i++) s[tid + i * 256] = scores[(size_t)q * N_ + tid + i * 256];
    __syncthreads();
    for (int r = 0; r < K_; r++) {
        float bv = -3.0e38f;
        int bi = 0;
        #pragma unroll
        for (int i = 0; i < 8; i++) {
            int j = tid + i * 256;
            float v = s[j];
            if (v > bv) { bv = v; bi = j; }
        }
        #pragma unroll
        for (int off = 32; off > 0; off >>= 1) {
            float ov = __shfl_down(bv, off, 64);
            int oi = __shfl_down(bi, off, 64);
            if (ov > bv || (ov == bv && oi < bi)) { bv = ov; bi = oi; }
        }
        if ((tid & 63) == 0) { rv[tid >> 6] = bv; ri[tid >> 6] = bi; }
        __syncthreads();
        if (tid == 0) {
            float mv = rv[0];
            int mi = ri[0];
            for (int w2 = 1; w2 < 4; w2++)
                if (rv[w2] > mv || (rv[w2] == mv && ri[w2] < mi)) { mv = rv[w2]; mi = ri[w2]; }
            lv[r] = mv; li[r] = mi;
            s[mi] = -3.0e38f;
        }
        __syncthreads();
    }
    if (tid == 0) {
        float m = lv[0];
        float e[K_];
        float sum = 0.f;
        for (int i = 0; i < K_; i++) { e[i] = expf(lv[i] - m); sum += e[i]; }
        float isum = 1.0f / sum;
        for (int i = 0; i < K_; i++) {
            wout[q * K_ + i] = e[i] * isum;
            iout[q * K_ + i] = li[i];
        }
    }
}

// ---------------- K4: A_sum[n,m] = sum_r adjacency[r,n,m] --------------
__global__ __launch_bounds__(256) void k_asum(const float* __restrict__ adj,
                                              float* __restrict__ asum) {
    size_t i = (size_t)blockIdx.x * 256 + threadIdx.x;  // float4 index, total N*N/4
    const float4* a4 = (const float4*)adj;
    const size_t plane = (size_t)N_ * N_ / 4;
    float4 acc = {0.f, 0.f, 0.f, 0.f};
    #pragma unroll
    for (int r = 0; r < R_; r++) {
        float4 v = a4[(size_t)r * plane + i];
        acc.x += v.x; acc.y += v.y; acc.z += v.z; acc.w += v.w;
    }
    ((float4*)asum)[i] = acc;
}

// ---------------- K5: nei[q,:] = sum_k w_k * A_sum[idx_k,:] ------------
__global__ __launch_bounds__(256) void k_nei(const float* __restrict__ asum,
                                             const float* __restrict__ wv,
                                             const int* __restrict__ iv,
                                             float* __restrict__ nei) {
    int q = blockIdx.x, tid = threadIdx.x;
    __shared__ float wi[K_];
    __shared__ int ii[K_];
    if (tid < K_) { wi[tid] = wv[q * K_ + tid]; ii[tid] = iv[q * K_ + tid]; }
    __syncthreads();
    float4 acc0 = {0.f, 0.f, 0.f, 0.f};
    float4 acc1 = {0.f, 0.f, 0.f, 0.f};
    #pragma unroll
    for (int k = 0; k < K_; k++) {
        const float4* row = (const float4*)(asum + (size_t)ii[k] * N_);
        float wk = wi[k];
        float4 v0 = row[tid], v1 = row[tid + 256];
        acc0.x += wk * v0.x; acc0.y += wk * v0.y; acc0.z += wk * v0.z; acc0.w += wk * v0.w;
        acc1.x += wk * v1.x; acc1.y += wk * v1.y; acc1.z += wk * v1.z; acc1.w += wk * v1.w;
    }
    float4* dst = (float4*)(nei + (size_t)q * N_);
    dst[tid] = acc0;
    dst[tid + 256] = acc1;
}

// ---------------- K6: out_part[z] = nei (256 x 256-slice) @ keys -------
// Same spill-proof structure as k_scores. Split-K=8 into private partials
// (plain stores; atomics ping-pong across XCD L2s).
__global__ __launch_bounds__(256) void k_out_part(const float* __restrict__ nei,
                                                  const float* __restrict__ keys,
                                                  float* __restrict__ part) {
    __shared__ float Ast[BK_][68];   // A = nei, transposed stage
    __shared__ float Bst[BK_][68];   // B = keys, direct stage (k-major rows)
    int tid = threadIdx.x;
    int tx = tid & 15, ty = tid >> 4;
    int d0 = blockIdx.x * 64;
    int q0 = blockIdx.y * 64;
    int z = blockIdx.z;
    float acc[4][4] = {};
    for (int kb = z * (N_ / SPLITS_); kb < (z + 1) * (N_ / SPLITS_); kb += BK_) {
        #pragma unroll
        for (int e = 0; e < 2; e++) {
            int elem = tid + e * 256;
            int row = elem >> 3, c4 = elem & 7;
            float4 v = *(const float4*)(nei + (size_t)(q0 + row) * N_ + kb + c4 * 4);
            Ast[c4 * 4 + 0][row] = v.x; Ast[c4 * 4 + 1][row] = v.y;
            Ast[c4 * 4 + 2][row] = v.z; Ast[c4 * 4 + 3][row] = v.w;
        }
        #pragma unroll
        for (int e = 0; e < 2; e++) {
            int elem = tid + e * 256;
            int kr = elem >> 4, c4 = elem & 15;
            float4 v = *(const float4*)(keys + (size_t)(kb + kr) * D_ + d0 + c4 * 4);
            *(float4*)&Bst[kr][c4 * 4] = v;
        }
        __syncthreads();
        #pragma unroll 4
        for (int kk = 0; kk < BK_; kk++) {
            float4 a = *(const float4*)&Ast[kk][ty * 4];
            float4 b = *(const float4*)&Bst[kk][tx * 4];
            float av[4] = {a.x, a.y, a.z, a.w};
            float bv[4] = {b.x, b.y, b.z, b.w};
            #pragma unroll
            for (int i = 0; i < 4; i++)
                #pragma unroll
                for (int j = 0; j < 4; j++)
                    acc[i][j] += av[i] * bv[j];
        }
        __syncthreads();
    }
    float* base = part + (size_t)z * Q_ * D_;
    #pragma unroll
    for (int i = 0; i < 4; i++) {
        float4 v = {acc[i][0], acc[i][1], acc[i][2], acc[i][3]};
        *(float4*)(base + (size_t)(q0 + ty * 4 + i) * D_ + d0 + tx * 4) = v;
    }
}

// ---------------- K7: out = sum_z part[z] ------------------------------
__global__ __launch_bounds__(256) void k_reduce(const float* __restrict__ part,
                                                float* __restrict__ out) {
    int i = blockIdx.x * 256 + threadIdx.x;  // float4 index over Q_*D_/4 = 49152
    const float4* p4 = (const float4*)part;
    const int plane = Q_ * D_ / 4;
    float4 acc = {0.f, 0.f, 0.f, 0.f};
    #pragma unroll
    for (int z = 0; z < SPLITS_; z++) {
        float4 v = p4[(size_t)z * plane + i];
        acc.x += v.x; acc.y += v.y; acc.z += v.z; acc.w += v.w;
    }
    ((float4*)out)[i] = acc;
}

extern "C" void kernel_launch(void* const* d_in, const int* in_sizes, int n_in,
                              void* d_out, int out_size, void* d_ws, size_t ws_size,
                              hipStream_t stream) {
    const float* pos = (const float*)d_in[0];   // (4,64,768)
    const float* kp  = (const float*)d_in[1];   // (2048,768)
    const float* adj = (const float*)d_in[2];   // (12,2048,2048)
    // d_in[3] is k==16, hard-coded.
    float* out = (float*)d_out;

    float* ws     = (float*)d_ws;
    float* keys   = ws;                              // 1,572,864 f
    float* asum   = keys + (size_t)N_ * D_;          // 4,194,304 f (16 MB)
    float* scores = asum + (size_t)N_ * N_;          //   524,288 f
    float* nei    = scores + (size_t)Q_ * N_;        //   524,288 f
    float* wbuf   = nei + (size_t)Q_ * N_;           //     4,096 f
    int*   ibuf   = (int*)(wbuf + Q_ * K_);          //     4,096 i
    // Partial buffers for split-K output GEMM: 8 * 256*768 f = 6 MB.
    // Aliased onto asum (dead after k_nei; same-stream ordering makes it safe).
    float* part   = asum;

    k_norm<<<N_, 256, 0, stream>>>(kp, keys);
    k_scores<<<dim3(32, 4), 256, 0, stream>>>(pos, keys, scores);
    k_topk<<<Q_, 256, 0, stream>>>(scores, wbuf, ibuf);
    k_asum<<<4096, 256, 0, stream>>>(adj, asum);
    k_nei<<<Q_, 256, 0, stream>>>(asum, wbuf, ibuf, nei);
    k_out_part<<<dim3(12, 4, SPLITS_), 256, 0, stream>>>(nei, keys, part);
    k_reduce<<<192, 256, 0, stream>>>(part, out);
}

// Round 4
// 386.193 us; speedup vs baseline: 2.7477x; 1.0605x over previous
//
#include <hip/hip_runtime.h>
#include <math.h>

#define B_ 4
#define P_ 64
#define D_ 768
#define N_ 2048
#define R_ 12
#define K_ 16
#define Q_ 256  // B_*P_
#define SPLITS_ 8
#define BK_ 32
#define NEG_INF_ -3.0e38f

// ---------------- K1: normalize key rows (N rows of D) ----------------
__global__ __launch_bounds__(256) void k_norm(const float* __restrict__ kp,
                                              float* __restrict__ keys) {
    int row = blockIdx.x;
    int tid = threadIdx.x;
    const float* src = kp + (size_t)row * D_;
    float x0 = src[tid], x1 = src[tid + 256], x2 = src[tid + 512];
    float ss = x0 * x0 + x1 * x1 + x2 * x2;
    #pragma unroll
    for (int off = 32; off > 0; off >>= 1) ss += __shfl_down(ss, off, 64);
    __shared__ float sm[4];
    if ((tid & 63) == 0) sm[tid >> 6] = ss;
    __syncthreads();
    float tot = sm[0] + sm[1] + sm[2] + sm[3];
    float inv = 1.0f / sqrtf(tot + 1e-12f);
    float* dst = keys + (size_t)row * D_;
    dst[tid] = x0 * inv;
    dst[tid + 256] = x1 * inv;
    dst[tid + 512] = x2 * inv;
}

// ---------------- K2: scores = positions (256xD) @ keys^T (NxD) --------
// f32 (top-k selection is precision-critical). 64x64 tile, BK=32, 4x4/thread.
// Split-K=2 over D: grid 128->256 blocks (was leaving half the CUs idle);
// k_topk sums the two partial planes at load time.
__global__ __launch_bounds__(256) void k_scores(const float* __restrict__ pos,
                                                const float* __restrict__ keys,
                                                float* __restrict__ spart) {
    __shared__ float Ast[BK_][68];
    __shared__ float Bst[BK_][68];
    int tid = threadIdx.x;
    int tx = tid & 15, ty = tid >> 4;
    int n0 = blockIdx.x * 64, q0 = blockIdx.y * 64;
    int z = blockIdx.z;  // 0/1 -> D halves
    float acc[4][4] = {};
    for (int kb = z * (D_ / 2); kb < (z + 1) * (D_ / 2); kb += BK_) {
        #pragma unroll
        for (int e = 0; e < 2; e++) {
            int elem = tid + e * 256;
            int row = elem >> 3, c4 = elem & 7;
            float4 v = *(const float4*)(pos + (size_t)(q0 + row) * D_ + kb + c4 * 4);
            Ast[c4 * 4 + 0][row] = v.x; Ast[c4 * 4 + 1][row] = v.y;
            Ast[c4 * 4 + 2][row] = v.z; Ast[c4 * 4 + 3][row] = v.w;
        }
        #pragma unroll
        for (int e = 0; e < 2; e++) {
            int elem = tid + e * 256;
            int row = elem >> 3, c4 = elem & 7;
            float4 v = *(const float4*)(keys + (size_t)(n0 + row) * D_ + kb + c4 * 4);
            Bst[c4 * 4 + 0][row] = v.x; Bst[c4 * 4 + 1][row] = v.y;
            Bst[c4 * 4 + 2][row] = v.z; Bst[c4 * 4 + 3][row] = v.w;
        }
        __syncthreads();
        #pragma unroll 4
        for (int kk = 0; kk < BK_; kk++) {
            float4 a = *(const float4*)&Ast[kk][ty * 4];
            float4 b = *(const float4*)&Bst[kk][tx * 4];
            float av[4] = {a.x, a.y, a.z, a.w};
            float bv[4] = {b.x, b.y, b.z, b.w};
            #pragma unroll
            for (int i = 0; i < 4; i++)
                #pragma unroll
                for (int j = 0; j < 4; j++)
                    acc[i][j] += av[i] * bv[j];
        }
        __syncthreads();
    }
    float* base = spart + (size_t)z * Q_ * N_;
    #pragma unroll
    for (int i = 0; i < 4; i++) {
        float4 v = {acc[i][0], acc[i][1], acc[i][2], acc[i][3]};
        *(float4*)(base + (size_t)(q0 + ty * 4 + i) * N_ + n0 + tx * 4) = v;
    }
}

// ---------------- K3: top-16 + softmax per query (register-resident) ---
// Old version rescanned 2048 LDS floats + 3 block barriers per round x16.
// New: 8 vals/lane in registers; per-wave top-16 via shuffle butterflies,
// then one wave merges the 4x16 candidates. Ties -> smaller index (matches
// lax.top_k). One barrier total.
__global__ __launch_bounds__(256) void k_topk(const float* __restrict__ s0,
                                              const float* __restrict__ s1,
                                              float* __restrict__ wout,
                                              int* __restrict__ iout) {
    int q = blockIdx.x, tid = threadIdx.x;
    int w = tid >> 6, lane = tid & 63;
    int base = w * 512 + lane;
    const float* r0 = s0 + (size_t)q * N_;
    const float* r1 = s1 + (size_t)q * N_;
    float v[8];
    #pragma unroll
    for (int j = 0; j < 8; j++) {
        int n = base + j * 64;
        v[j] = r0[n] + r1[n];
    }
    __shared__ float cv[64];
    __shared__ int ci[64];
    for (int r = 0; r < K_; r++) {
        float bv = NEG_INF_;
        int bi = 0;
        #pragma unroll
        for (int j = 0; j < 8; j++) {
            int n = base + j * 64;
            if (v[j] > bv) { bv = v[j]; bi = n; }  // ascending n: first max kept
        }
        #pragma unroll
        for (int off = 1; off < 64; off <<= 1) {
            float ov = __shfl_xor(bv, off, 64);
            int oi = __shfl_xor(bi, off, 64);
            if (ov > bv || (ov == bv && oi < bi)) { bv = ov; bi = oi; }
        }
        if (lane == 0) { cv[w * K_ + r] = bv; ci[w * K_ + r] = bi; }
        #pragma unroll
        for (int j = 0; j < 8; j++)
            if (base + j * 64 == bi) v[j] = NEG_INF_;
    }
    __syncthreads();
    if (w == 0) {
        float mv = cv[lane];
        int mi = ci[lane];  // 64 candidates, all n distinct
        float sel_v = NEG_INF_;
        int sel_i = 0;
        for (int r = 0; r < K_; r++) {
            float bv = mv;
            int bi = mi;
            #pragma unroll
            for (int off = 1; off < 64; off <<= 1) {
                float ov = __shfl_xor(bv, off, 64);
                int oi = __shfl_xor(bi, off, 64);
                if (ov > bv || (ov == bv && oi < bi)) { bv = ov; bi = oi; }
            }
            if (lane == r) { sel_v = bv; sel_i = bi; }
            if (mi == bi) mv = NEG_INF_;
        }
        // softmax over lanes 0..15 (lane 0 holds the max: rounds descend)
        float m = __shfl(sel_v, 0, 64);
        float e = (lane < K_) ? expf(sel_v - m) : 0.0f;
        float sum = e;
        #pragma unroll
        for (int off = 1; off < 64; off <<= 1) sum += __shfl_xor(sum, off, 64);
        if (lane < K_) {
            wout[q * K_ + lane] = e / sum;
            iout[q * K_ + lane] = sel_i;
        }
    }
}

// ---------------- K4: A_sum[n,m] = sum_r adjacency[r,n,m] --------------
// 201 MB mandatory read -> HBM floor (~32 us). Leave alone.
__global__ __launch_bounds__(256) void k_asum(const float* __restrict__ adj,
                                              float* __restrict__ asum) {
    size_t i = (size_t)blockIdx.x * 256 + threadIdx.x;
    const float4* a4 = (const float4*)adj;
    const size_t plane = (size_t)N_ * N_ / 4;
    float4 acc = {0.f, 0.f, 0.f, 0.f};
    #pragma unroll
    for (int r = 0; r < R_; r++) {
        float4 v = a4[(size_t)r * plane + i];
        acc.x += v.x; acc.y += v.y; acc.z += v.z; acc.w += v.w;
    }
    ((float4*)asum)[i] = acc;
}

// ---------------- K5: nei[q,:] = sum_k w_k * A_sum[idx_k,:] ------------
__global__ __launch_bounds__(256) void k_nei(const float* __restrict__ asum,
                                             const float* __restrict__ wv,
                                             const int* __restrict__ iv,
                                             float* __restrict__ nei) {
    int q = blockIdx.x, tid = threadIdx.x;
    __shared__ float wi[K_];
    __shared__ int ii[K_];
    if (tid < K_) { wi[tid] = wv[q * K_ + tid]; ii[tid] = iv[q * K_ + tid]; }
    __syncthreads();
    float4 acc0 = {0.f, 0.f, 0.f, 0.f};
    float4 acc1 = {0.f, 0.f, 0.f, 0.f};
    #pragma unroll
    for (int k = 0; k < K_; k++) {
        const float4* row = (const float4*)(asum + (size_t)ii[k] * N_);
        float wk = wi[k];
        float4 v0 = row[tid], v1 = row[tid + 256];
        acc0.x += wk * v0.x; acc0.y += wk * v0.y; acc0.z += wk * v0.z; acc0.w += wk * v0.w;
        acc1.x += wk * v1.x; acc1.y += wk * v1.y; acc1.z += wk * v1.z; acc1.w += wk * v1.w;
    }
    float4* dst = (float4*)(nei + (size_t)q * N_);
    dst[tid] = acc0;
    dst[tid + 256] = acc1;
}

// ---------------- K6: out_part[z] = nei (256 x 256-slice) @ keys -------
// Split-K=8 into private partials (plain stores; atomics ping-pong across
// non-coherent XCD L2s -> was 1.5 GB of HBM traffic).
__global__ __launch_bounds__(256) void k_out_part(const float* __restrict__ nei,
                                                  const float* __restrict__ keys,
                                                  float* __restrict__ part) {
    __shared__ float Ast[BK_][68];
    __shared__ float Bst[BK_][68];
    int tid = threadIdx.x;
    int tx = tid & 15, ty = tid >> 4;
    int d0 = blockIdx.x * 64;
    int q0 = blockIdx.y * 64;
    int z = blockIdx.z;
    float acc[4][4] = {};
    for (int kb = z * (N_ / SPLITS_); kb < (z + 1) * (N_ / SPLITS_); kb += BK_) {
        #pragma unroll
        for (int e = 0; e < 2; e++) {
            int elem = tid + e * 256;
            int row = elem >> 3, c4 = elem & 7;
            float4 v = *(const float4*)(nei + (size_t)(q0 + row) * N_ + kb + c4 * 4);
            Ast[c4 * 4 + 0][row] = v.x; Ast[c4 * 4 + 1][row] = v.y;
            Ast[c4 * 4 + 2][row] = v.z; Ast[c4 * 4 + 3][row] = v.w;
        }
        #pragma unroll
        for (int e = 0; e < 2; e++) {
            int elem = tid + e * 256;
            int kr = elem >> 4, c4 = elem & 15;
            float4 v = *(const float4*)(keys + (size_t)(kb + kr) * D_ + d0 + c4 * 4);
            *(float4*)&Bst[kr][c4 * 4] = v;
        }
        __syncthreads();
        #pragma unroll 4
        for (int kk = 0; kk < BK_; kk++) {
            float4 a = *(const float4*)&Ast[kk][ty * 4];
            float4 b = *(const float4*)&Bst[kk][tx * 4];
            float av[4] = {a.x, a.y, a.z, a.w};
            float bv[4] = {b.x, b.y, b.z, b.w};
            #pragma unroll
            for (int i = 0; i < 4; i++)
                #pragma unroll
                for (int j = 0; j < 4; j++)
                    acc[i][j] += av[i] * bv[j];
        }
        __syncthreads();
    }
    float* base = part + (size_t)z * Q_ * D_;
    #pragma unroll
    for (int i = 0; i < 4; i++) {
        float4 v = {acc[i][0], acc[i][1], acc[i][2], acc[i][3]};
        *(float4*)(base + (size_t)(q0 + ty * 4 + i) * D_ + d0 + tx * 4) = v;
    }
}

// ---------------- K7: out = sum_z part[z] ------------------------------
__global__ __launch_bounds__(256) void k_reduce(const float* __restrict__ part,
                                                float* __restrict__ out) {
    int i = blockIdx.x * 256 + threadIdx.x;
    const float4* p4 = (const float4*)part;
    const int plane = Q_ * D_ / 4;
    float4 acc = {0.f, 0.f, 0.f, 0.f};
    #pragma unroll
    for (int z = 0; z < SPLITS_; z++) {
        float4 v = p4[(size_t)z * plane + i];
        acc.x += v.x; acc.y += v.y; acc.z += v.z; acc.w += v.w;
    }
    ((float4*)out)[i] = acc;
}

extern "C" void kernel_launch(void* const* d_in, const int* in_sizes, int n_in,
                              void* d_out, int out_size, void* d_ws, size_t ws_size,
                              hipStream_t stream) {
    const float* pos = (const float*)d_in[0];   // (4,64,768)
    const float* kp  = (const float*)d_in[1];   // (2048,768)
    const float* adj = (const float*)d_in[2];   // (12,2048,2048)
    // d_in[3] is k==16, hard-coded.
    float* out = (float*)d_out;

    float* ws     = (float*)d_ws;
    float* keys   = ws;                              // 1,572,864 f
    float* asum   = keys + (size_t)N_ * D_;          // 4,194,304 f (16 MB)
    float* spart  = asum + (size_t)N_ * N_;          // 2 x 524,288 f (split-K scores)
    float* nei    = spart + 2 * (size_t)Q_ * N_;     //   524,288 f
    float* wbuf   = nei + (size_t)Q_ * N_;           //     4,096 f
    int*   ibuf   = (int*)(wbuf + Q_ * K_);          //     4,096 i
    // Split-K output partials (8 * 256*768 f = 6 MB) aliased onto asum
    // (dead after k_nei; same-stream ordering makes it safe).
    float* part   = asum;

    k_norm<<<N_, 256, 0, stream>>>(kp, keys);
    k_scores<<<dim3(32, 4, 2), 256, 0, stream>>>(pos, keys, spart);
    k_topk<<<Q_, 256, 0, stream>>>(spart, spart + (size_t)Q_ * N_, wbuf, ibuf);
    k_asum<<<4096, 256, 0, stream>>>(adj, asum);
    k_nei<<<Q_, 256, 0, stream>>>(asum, wbuf, ibuf, nei);
    k_out_part<<<dim3(12, 4, SPLITS_), 256, 0, stream>>>(nei, keys, part);
    k_reduce<<<192, 256, 0, stream>>>(part, out);
}